// Round 8
// baseline (112.813 us; speedup 1.0000x reference)
//
#include <hip/hip_runtime.h>
#include <math.h>

#define BATCH 4
#define LQ 2048
#define LK 2048
#define DIM 16
#define HEADS 2
#define DH 8
#define EPS 1e-5f

typedef float fvec4 __attribute__((ext_vector_type(4)));
typedef unsigned int uvec4 __attribute__((ext_vector_type(4)));
typedef unsigned int uvec2 __attribute__((ext_vector_type(2)));

__device__ __forceinline__ unsigned pack_bf16(float lo, float hi) {
    union { float f; unsigned u; } a, b;
    a.f = lo; b.f = hi;
    unsigned ua = (a.u + 0x7fffu + ((a.u >> 16) & 1u)) >> 16;
    unsigned ub = (b.u + 0x7fffu + ((b.u >> 16) & 1u)) & 0xffff0000u;
    return ua | ub;
}
__device__ __forceinline__ float bf_lo(unsigned u) {
    union { unsigned u; float f; } c; c.u = u << 16; return c.f;
}
__device__ __forceinline__ float bf_hi(unsigned u) {
    union { unsigned u; float f; } c; c.u = u & 0xffff0000u; return c.f;
}

// ---------------- Kernel A: fused LayerNorm + Linear for q,k,v ------------
__global__ __launch_bounds__(256) void ln_proj3_kernel(
    const float* __restrict__ xq, const float* __restrict__ xk,
    const float* __restrict__ xv,
    const float* __restrict__ gq, const float* __restrict__ bq_ln,
    const float* __restrict__ gk, const float* __restrict__ bk_ln,
    const float* __restrict__ gv, const float* __restrict__ bv_ln,
    const float* __restrict__ Wq, const float* __restrict__ bq,
    const float* __restrict__ Wk, const float* __restrict__ bk,
    const float* __restrict__ Wv, const float* __restrict__ bv,
    float* __restrict__ Qb, float* __restrict__ Kb, float* __restrict__ Vb,
    float* __restrict__ q0)
{
    const int gid = blockIdx.x * blockDim.x + threadIdx.x;
    const int which = gid >> 13;          // 0=q 1=k 2=v
    const int r     = gid & 8191;

    const float* x; const float* g; const float* bl;
    const float* W; const float* bb; float* outp; float scale;
    if (which == 0)      { x = xq; g = gq; bl = bq_ln; W = Wq; bb = bq; outp = Qb; scale = 0.35355339059327373f; }
    else if (which == 1) { x = xk; g = gk; bl = bk_ln; W = Wk; bb = bk; outp = Kb; scale = 1.0f; }
    else                 { x = xv; g = gv; bl = bv_ln; W = Wv; bb = bv; outp = Vb; scale = 1.0f; }

    float xv16[16];
    const float4* xp = (const float4*)(x + (size_t)r * 16);
#pragma unroll
    for (int i = 0; i < 4; ++i) {
        float4 t = xp[i];
        xv16[4*i+0] = t.x; xv16[4*i+1] = t.y; xv16[4*i+2] = t.z; xv16[4*i+3] = t.w;
    }
    float m = 0.f;
#pragma unroll
    for (int i = 0; i < 16; ++i) m += xv16[i];
    m *= (1.f / 16.f);
    float var = 0.f;
#pragma unroll
    for (int i = 0; i < 16; ++i) { float d = xv16[i] - m; var += d * d; }
    var *= (1.f / 16.f);
    float rs = rsqrtf(var + EPS);

    float xn[16];
#pragma unroll
    for (int i = 0; i < 16; ++i) xn[i] = (xv16[i] - m) * rs * g[i] + bl[i];

    if (which == 0) {
        float4* op = (float4*)(q0 + (size_t)r * 16);
#pragma unroll
        for (int i = 0; i < 4; ++i) {
            float4 t; t.x = xn[4*i+0]; t.y = xn[4*i+1]; t.z = xn[4*i+2]; t.w = xn[4*i+3];
            op[i] = t;
        }
    }

    const int b = r >> 11;
    const int l = r & 2047;
#pragma unroll
    for (int j = 0; j < 16; ++j) {
        float acc = bb[j];
#pragma unroll
        for (int i = 0; i < 16; ++i) acc += xn[i] * W[j * 16 + i];
        acc *= scale;
        int h = j >> 3, d = j & 7;
        outp[((((size_t)b * HEADS + h) * 2048) + l) * DH + d] = acc;
    }
}

// ---------------- Kernel B: bf16 K/V full panel in LDS, ONE barrier -------
// r6 skeleton (512 thr, 8 waves, wave=row, 4-col lane groups) but K/V stored
// bf16 packed-by-dim-pair: Kp[p][col] = (K[2p][col], K[2p+1][col]).
// Full 2048-col panel = 64KB -> single stage, single barrier, no chunk
// phases, and half the LDS read bytes of r6's fp32 SoA.
__device__ __forceinline__ float wave_sum(float v) {
#pragma unroll
    for (int off = 32; off > 0; off >>= 1) v += __shfl_xor(v, off);
    return v;
}

// (512,2): proven no-spill cap (>=128 VGPR). (512,4)/(1024,4) forced 64-cap
// and spilled (r3, r5). Do not change.
__global__ __launch_bounds__(512, 2) void attn_kernel(
    const float* __restrict__ Q,    // (B,H,LQ,DH) pre-scaled by 1/sqrt(dh)
    const float* __restrict__ K,    // (B,H,LK,DH)
    const float* __restrict__ V,    // (B,H,LK,DH)
    const float* __restrict__ w,    // (B,H,LQ,LK)
    const float* __restrict__ mask, // (B,H,LQ,LK)
    float* __restrict__ attn_out,   // (B,H,LQ,LK)
    float* __restrict__ ctx)        // (B,LQ,H,DH) == (B,LQ,16)
{
    __shared__ unsigned Kp[4][2048];   // 32 KB
    __shared__ unsigned Vp[4][2048];   // 32 KB

    const int t    = threadIdx.x;
    const int lane = t & 63;
    const int wid  = t >> 6;                 // 0..7, one q-row per wave
    const int bh   = blockIdx.x >> 8;        // 8 panels x 256 blocks
    const int qbase= (blockIdx.x & 255) << 3;
    const int q    = qbase + wid;
    const int rowid= (bh << 11) + q;
    const int h    = bh & (HEADS - 1);
    const int b    = bh >> 1;

    // ---- stage full panel as bf16: thread t covers col pairs (2t, 2t+1)
    //      and (2t+1024, 2t+1025) ----
    {
        const fvec4* Kg = (const fvec4*)(K + (size_t)bh * LK * DH);
        const fvec4* Vg = (const fvec4*)(V + (size_t)bh * LK * DH);
#pragma unroll
        for (int half = 0; half < 2; ++half) {
            const int c = 2 * t + (half << 10);
            fvec4 kA0 = Kg[(size_t)c * 2 + 0],     kA1 = Kg[(size_t)c * 2 + 1];
            fvec4 kB0 = Kg[(size_t)(c + 1) * 2 + 0], kB1 = Kg[(size_t)(c + 1) * 2 + 1];
            fvec4 vA0 = Vg[(size_t)c * 2 + 0],     vA1 = Vg[(size_t)c * 2 + 1];
            fvec4 vB0 = Vg[(size_t)(c + 1) * 2 + 0], vB1 = Vg[(size_t)(c + 1) * 2 + 1];
            uvec2 u;
            u.x = pack_bf16(kA0.x, kA0.y); u.y = pack_bf16(kB0.x, kB0.y);
            *(uvec2*)&Kp[0][c] = u;
            u.x = pack_bf16(kA0.z, kA0.w); u.y = pack_bf16(kB0.z, kB0.w);
            *(uvec2*)&Kp[1][c] = u;
            u.x = pack_bf16(kA1.x, kA1.y); u.y = pack_bf16(kB1.x, kB1.y);
            *(uvec2*)&Kp[2][c] = u;
            u.x = pack_bf16(kA1.z, kA1.w); u.y = pack_bf16(kB1.z, kB1.w);
            *(uvec2*)&Kp[3][c] = u;
            u.x = pack_bf16(vA0.x, vA0.y); u.y = pack_bf16(vB0.x, vB0.y);
            *(uvec2*)&Vp[0][c] = u;
            u.x = pack_bf16(vA0.z, vA0.w); u.y = pack_bf16(vB0.z, vB0.w);
            *(uvec2*)&Vp[1][c] = u;
            u.x = pack_bf16(vA1.x, vA1.y); u.y = pack_bf16(vB1.x, vB1.y);
            *(uvec2*)&Vp[2][c] = u;
            u.x = pack_bf16(vA1.z, vA1.w); u.y = pack_bf16(vB1.z, vB1.w);
            *(uvec2*)&Vp[3][c] = u;
        }
    }

    const float* Qrow = Q + (size_t)rowid * DH;
    float qv[8];
#pragma unroll
    for (int i = 0; i < 8; ++i) qv[i] = Qrow[i];

    const float* wrow = w    + (size_t)rowid * LK;
    const float* mrow = mask + (size_t)rowid * LK;

    __syncthreads();   // the ONLY barrier

    fvec4 ebuf[8];
    float sum = 0.f;
    float cd[8] = {0,0,0,0,0,0,0,0};

#pragma unroll
    for (int i = 0; i < 8; ++i) {
        const int cb = (i << 8) + (lane << 2);   // lane's 4 consecutive cols
        fvec4 wv = __builtin_nontemporal_load((const fvec4*)(wrow + cb));
        fvec4 mv = __builtin_nontemporal_load((const fvec4*)(mrow + cb));
        fvec4 s = wv + mv;
#pragma unroll
        for (int p = 0; p < 4; ++p) {
            uvec4 kk = *(const uvec4*)&Kp[p][cb];
            const float qa = qv[2 * p], qb = qv[2 * p + 1];
#pragma unroll
            for (int j = 0; j < 4; ++j) {
                s[j] += qa * bf_lo(kk[j]) + qb * bf_hi(kk[j]);
            }
        }
        // softmax shift-invariant; |s| ~< 10, fp32 exp safe
        fvec4 e;
        e.x = __expf(s.x); e.y = __expf(s.y); e.z = __expf(s.z); e.w = __expf(s.w);
        ebuf[i] = e;
        sum += e.x + e.y + e.z + e.w;
#pragma unroll
        for (int p = 0; p < 4; ++p) {
            uvec4 vv = *(const uvec4*)&Vp[p][cb];
            float a0 = 0.f, a1 = 0.f;
#pragma unroll
            for (int j = 0; j < 4; ++j) {
                a0 += e[j] * bf_lo(vv[j]);
                a1 += e[j] * bf_hi(vv[j]);
            }
            cd[2 * p]     += a0;
            cd[2 * p + 1] += a1;
        }
    }

    sum = wave_sum(sum);
    const float inv = 1.f / sum;

    // float4 nontemporal stores: don't evict the w/mask stream from L2/L3.
    float* arow = attn_out + (size_t)rowid * LK;
#pragma unroll
    for (int i = 0; i < 8; ++i) {
        const int cb = (i << 8) + (lane << 2);
        __builtin_nontemporal_store(ebuf[i] * inv, (fvec4*)(arow + cb));
    }

#pragma unroll
    for (int d = 0; d < 8; ++d) cd[d] = wave_sum(cd[d]) * inv;
    if (lane == 0) {
        float* cp = ctx + ((((size_t)b * LQ + q) * HEADS) + h) * DH;
        fvec4 t0; t0.x = cd[0]; t0.y = cd[1]; t0.z = cd[2]; t0.w = cd[3];
        fvec4 t1; t1.x = cd[4]; t1.y = cd[5]; t1.z = cd[6]; t1.w = cd[7];
        ((fvec4*)cp)[0] = t0;
        ((fvec4*)cp)[1] = t1;
    }
}

// ---------------- Kernel C: output projection + residual ------------------
__global__ __launch_bounds__(256) void out_kernel(
    const float* __restrict__ ctx,  // (B,LQ,16)
    const float* __restrict__ Wo,   // (16,16)
    const float* __restrict__ bo,   // (16,)
    const float* __restrict__ q0,   // (B,LQ,16)
    float* __restrict__ out, int n)
{
    int gid = blockIdx.x * blockDim.x + threadIdx.x;
    if (gid >= n) return;
    int row = gid >> 4, j = gid & 15;
    const float* c = ctx + (size_t)row * 16;
    float acc = bo[j];
#pragma unroll
    for (int i = 0; i < 16; ++i) acc += c[i] * Wo[j * 16 + i];
    out[gid] = acc + q0[gid];
}

extern "C" void kernel_launch(void* const* d_in, const int* in_sizes, int n_in,
                              void* d_out, int out_size, void* d_ws, size_t ws_size,
                              hipStream_t stream) {
    const float* query = (const float*)d_in[0];
    const float* key_  = (const float*)d_in[1];
    const float* value = (const float*)d_in[2];
    const float* w     = (const float*)d_in[3];
    const float* mask  = (const float*)d_in[4];
    const float* ln_qg = (const float*)d_in[5];
    const float* ln_qb = (const float*)d_in[6];
    const float* ln_kg = (const float*)d_in[7];
    const float* ln_kb = (const float*)d_in[8];
    const float* ln_vg = (const float*)d_in[9];
    const float* ln_vb = (const float*)d_in[10];
    const float* Wq = (const float*)d_in[11];
    const float* bq = (const float*)d_in[12];
    const float* Wk = (const float*)d_in[13];
    const float* bk = (const float*)d_in[14];
    const float* Wv = (const float*)d_in[15];
    const float* bv = (const float*)d_in[16];
    const float* Wo = (const float*)d_in[17];
    const float* bo = (const float*)d_in[18];

    float* out  = (float*)d_out;                       // (B,LQ,16) first
    float* attn = out + (size_t)BATCH * LQ * DIM;      // then (B,H,LQ,LK)

    const size_t NE = (size_t)BATCH * LQ * DIM;        // 131072
    float* ws  = (float*)d_ws;
    float* Qb  = ws;            // (B,H,LQ,DH)
    float* Kb  = Qb + NE;       // (B,H,LK,DH)
    float* Vb  = Kb + NE;       // (B,H,LK,DH)
    float* q0  = Vb + NE;       // (B,LQ,16)
    float* ctx = q0 + NE;       // (B,LQ,16)

    ln_proj3_kernel<<<(3 * 8192) / 256, 256, 0, stream>>>(
        query, key_, value,
        ln_qg, ln_qb, ln_kg, ln_kb, ln_vg, ln_vb,
        Wq, bq, Wk, bk, Wv, bv,
        Qb, Kb, Vb, q0);

    // 2048 blocks: 8 bh panels x 256 blocks, 8 q-rows per block
    attn_kernel<<<BATCH * HEADS * LQ / 8, 512, 0, stream>>>(
        Qb, Kb, Vb, w, mask, attn, ctx);

    out_kernel<<<((int)NE + 255) / 256, 256, 0, stream>>>(
        ctx, Wo, bo, q0, out, (int)NE);
}

// Round 10
// 85.129 us; speedup vs baseline: 1.3252x; 1.3252x over previous
//
#include <hip/hip_runtime.h>
#include <math.h>

#define BATCH 4
#define LQ 2048
#define LK 2048
#define DIM 16
#define HEADS 2
#define DH 8
#define EPS 1e-5f

typedef float fvec4 __attribute__((ext_vector_type(4)));
typedef unsigned int uvec4 __attribute__((ext_vector_type(4)));
typedef unsigned int uvec2 __attribute__((ext_vector_type(2)));
typedef __fp16 hvec2 __attribute__((ext_vector_type(2)));   // matches builtin sigs

__device__ __forceinline__ hvec2 u2h(unsigned u) {
    union { unsigned u; hvec2 h; } c; c.u = u; return c.h;
}
__device__ __forceinline__ unsigned h2u(hvec2 h) {
    union { unsigned u; hvec2 h; } c; c.h = h; return c.u;
}

// ---------------- Kernel A: fused LayerNorm + Linear for q,k,v ------------
// Q: fp32 (B,H,L,DH) pre-scaled. K: fp16 half2 dim-pairs Kh[bh][p][col]
// (p = dim pair 0..3). V: fp16 scalar Vh[bh][d][col]. Both attn-ready.
__global__ __launch_bounds__(256) void ln_proj3_kernel(
    const float* __restrict__ xq, const float* __restrict__ xk,
    const float* __restrict__ xv,
    const float* __restrict__ gq, const float* __restrict__ bq_ln,
    const float* __restrict__ gk, const float* __restrict__ bk_ln,
    const float* __restrict__ gv, const float* __restrict__ bv_ln,
    const float* __restrict__ Wq, const float* __restrict__ bq,
    const float* __restrict__ Wk, const float* __restrict__ bk,
    const float* __restrict__ Wv, const float* __restrict__ bv,
    float* __restrict__ Qb, unsigned* __restrict__ Kh,
    unsigned short* __restrict__ Vh, float* __restrict__ q0)
{
    const int gid = blockIdx.x * blockDim.x + threadIdx.x;
    const int which = gid >> 13;          // 0=q 1=k 2=v (uniform per block)
    const int r     = gid & 8191;

    const float* x; const float* g; const float* bl;
    const float* W; const float* bb; float scale;
    if (which == 0)      { x = xq; g = gq; bl = bq_ln; W = Wq; bb = bq; scale = 0.35355339059327373f; }
    else if (which == 1) { x = xk; g = gk; bl = bk_ln; W = Wk; bb = bk; scale = 1.0f; }
    else                 { x = xv; g = gv; bl = bv_ln; W = Wv; bb = bv; scale = 1.0f; }

    float xv16[16];
    const float4* xp = (const float4*)(x + (size_t)r * 16);
#pragma unroll
    for (int i = 0; i < 4; ++i) {
        float4 t = xp[i];
        xv16[4*i+0] = t.x; xv16[4*i+1] = t.y; xv16[4*i+2] = t.z; xv16[4*i+3] = t.w;
    }
    float m = 0.f;
#pragma unroll
    for (int i = 0; i < 16; ++i) m += xv16[i];
    m *= (1.f / 16.f);
    float var = 0.f;
#pragma unroll
    for (int i = 0; i < 16; ++i) { float d = xv16[i] - m; var += d * d; }
    var *= (1.f / 16.f);
    float rs = rsqrtf(var + EPS);

    float xn[16];
#pragma unroll
    for (int i = 0; i < 16; ++i) xn[i] = (xv16[i] - m) * rs * g[i] + bl[i];

    if (which == 0) {
        float4* op = (float4*)(q0 + (size_t)r * 16);
#pragma unroll
        for (int i = 0; i < 4; ++i) {
            float4 t; t.x = xn[4*i+0]; t.y = xn[4*i+1]; t.z = xn[4*i+2]; t.w = xn[4*i+3];
            op[i] = t;
        }
    }

    float pr[16];
#pragma unroll
    for (int j = 0; j < 16; ++j) {
        float acc = bb[j];
#pragma unroll
        for (int i = 0; i < 16; ++i) acc += xn[i] * W[j * 16 + i];
        pr[j] = acc * scale;
    }

    const int b = r >> 11;
    const int l = r & 2047;
    if (which == 0) {
#pragma unroll
        for (int j = 0; j < 16; ++j) {
            int h = j >> 3, d = j & 7;
            Qb[((((size_t)b * HEADS + h) * 2048) + l) * DH + d] = pr[j];
        }
    } else if (which == 1) {
#pragma unroll
        for (int h = 0; h < 2; ++h) {
            unsigned* Kpan = Kh + ((size_t)(b * 2 + h)) * 8192;
#pragma unroll
            for (int p = 0; p < 4; ++p) {
                hvec2 hk = __builtin_amdgcn_cvt_pkrtz(pr[h * 8 + 2 * p], pr[h * 8 + 2 * p + 1]);
                Kpan[p * 2048 + l] = h2u(hk);
            }
        }
    } else {
#pragma unroll
        for (int h = 0; h < 2; ++h) {
            unsigned short* Vpan = Vh + ((size_t)(b * 2 + h)) * 16384;
#pragma unroll
            for (int d = 0; d < 8; ++d) {
                union { __fp16 h; unsigned short u; } cv;
                cv.h = (__fp16)pr[h * 8 + d];
                Vpan[d * 2048 + l] = cv.u;
            }
        }
    }
}

// ---------------- Kernel B: fp16 K/V LDS (32KB chunk) + v_dot2 ------------
__device__ __forceinline__ float wave_sum(float v) {
#pragma unroll
    for (int off = 32; off > 0; off >>= 1) v += __shfl_xor(v, off);
    return v;
}

// (512,2): proven no-spill cap. (512,4)/(1024,4) forced 64-VGPR cap and
// spilled (r3, r5). Do not change.
__global__ __launch_bounds__(512, 2) void attn_kernel(
    const float* __restrict__ Q,          // (B,H,LQ,DH) pre-scaled
    const unsigned* __restrict__ Kh,      // [bh][p][2048] half2 dim-pairs
    const unsigned* __restrict__ Vh,      // [bh][d][1024] half2 col-pairs (u32 view)
    const float* __restrict__ w,
    const float* __restrict__ mask,
    float* __restrict__ attn_out,
    float* __restrict__ ctx)
{
    __shared__ unsigned Kp[4][1024];   // 16 KB: dims pair p, 1024-col chunk
    __shared__ unsigned Vp[8][512];    // 16 KB: dim d, col-pairs

    const int t    = threadIdx.x;
    const int lane = t & 63;
    const int wid  = t >> 6;                 // 0..7, one q-row per wave
    const int bh   = blockIdx.x >> 8;        // 8 panels x 256 blocks
    const int qbase= (blockIdx.x & 255) << 3;
    const int q    = qbase + wid;
    const int rowid= (bh << 11) + q;
    const int h    = bh & (HEADS - 1);
    const int b    = bh >> 1;

    const unsigned* Kpan = Kh + (size_t)bh * 8192;
    const unsigned* Vpan = Vh + (size_t)bh * 8192;

    // q -> 4 packed half2 dim-pairs
    const float* Qrow = Q + (size_t)rowid * DH;
    hvec2 qpk[4];
#pragma unroll
    for (int p = 0; p < 4; ++p) qpk[p] = __builtin_amdgcn_cvt_pkrtz(Qrow[2 * p], Qrow[2 * p + 1]);

    const float* wrow = w    + (size_t)rowid * LK;
    const float* mrow = mask + (size_t)rowid * LK;

    unsigned epk[16];            // e as half2 col-pairs: PV operand + store staging
    float sum = 0.f;
    float cd[8] = {0,0,0,0,0,0,0,0};

#pragma unroll
    for (int chunk = 0; chunk < 2; ++chunk) {
        if (chunk) __syncthreads();
        // ---- stage 1024-col chunk (pure copies, no conversion) ----
        {
            const int gcol = (chunk << 10) + (t << 1);   // thread covers 2 cols
#pragma unroll
            for (int p = 0; p < 4; ++p)
                *(uvec2*)&Kp[p][t << 1] = *(const uvec2*)&Kpan[p * 2048 + gcol];
#pragma unroll
            for (int d = 0; d < 8; ++d)
                Vp[d][t] = Vpan[d * 1024 + (chunk << 9) + t];
        }
        __syncthreads();
        // ---- compute: 4 groups of 4 consecutive cols per lane ----
#pragma unroll
        for (int i = 0; i < 4; ++i) {
            const int cb  = (i << 8) + (lane << 2);
            const int col = (chunk << 10) + cb;
            fvec4 wv = __builtin_nontemporal_load((const fvec4*)(wrow + col));
            fvec4 mv = __builtin_nontemporal_load((const fvec4*)(mrow + col));
            uvec4 kk0 = *(const uvec4*)&Kp[0][cb];
            uvec4 kk1 = *(const uvec4*)&Kp[1][cb];
            uvec4 kk2 = *(const uvec4*)&Kp[2][cb];
            uvec4 kk3 = *(const uvec4*)&Kp[3][cb];
            float e[4];
#pragma unroll
            for (int j = 0; j < 4; ++j) {
                // -4 shift: softmax-invariant, keeps e in fp16 range
                float sj = wv[j] + mv[j] - 4.0f;
                sj = __builtin_amdgcn_fdot2(qpk[0], u2h(kk0[j]), sj, false);
                sj = __builtin_amdgcn_fdot2(qpk[1], u2h(kk1[j]), sj, false);
                sj = __builtin_amdgcn_fdot2(qpk[2], u2h(kk2[j]), sj, false);
                sj = __builtin_amdgcn_fdot2(qpk[3], u2h(kk3[j]), sj, false);
                e[j] = __expf(sj);
            }
            sum += (e[0] + e[1]) + (e[2] + e[3]);
            hvec2 e01 = __builtin_amdgcn_cvt_pkrtz(e[0], e[1]);
            hvec2 e23 = __builtin_amdgcn_cvt_pkrtz(e[2], e[3]);
            const int g = (chunk << 2) + i;
            epk[2 * g]     = h2u(e01);
            epk[2 * g + 1] = h2u(e23);
            const int cp = cb >> 1;
#pragma unroll
            for (int d = 0; d < 8; ++d) {
                uvec2 vv = *(const uvec2*)&Vp[d][cp];
                cd[d] = __builtin_amdgcn_fdot2(e01, u2h(vv.x), cd[d], false);
                cd[d] = __builtin_amdgcn_fdot2(e23, u2h(vv.y), cd[d], false);
            }
        }
    }

    sum = wave_sum(sum);
    const float inv = 1.f / sum;

    // normalized attn row: unpack fp16 e, scale, nontemporal fvec4 stores
    float* arow = attn_out + (size_t)rowid * LK;
#pragma unroll
    for (int g = 0; g < 8; ++g) {
        const int col = ((g >> 2) << 10) + ((g & 3) << 8) + (lane << 2);
        hvec2 e01 = u2h(epk[2 * g]), e23 = u2h(epk[2 * g + 1]);
        fvec4 o;
        o.x = (float)e01.x * inv; o.y = (float)e01.y * inv;
        o.z = (float)e23.x * inv; o.w = (float)e23.y * inv;
        __builtin_nontemporal_store(o, (fvec4*)(arow + col));
    }

#pragma unroll
    for (int d = 0; d < 8; ++d) cd[d] = wave_sum(cd[d]) * inv;
    if (lane == 0) {
        float* cp = ctx + ((((size_t)b * LQ + q) * HEADS) + h) * DH;
        fvec4 t0; t0.x = cd[0]; t0.y = cd[1]; t0.z = cd[2]; t0.w = cd[3];
        fvec4 t1; t1.x = cd[4]; t1.y = cd[5]; t1.z = cd[6]; t1.w = cd[7];
        ((fvec4*)cp)[0] = t0;
        ((fvec4*)cp)[1] = t1;
    }
}

// ---------------- Kernel C: output projection + residual ------------------
__global__ __launch_bounds__(256) void out_kernel(
    const float* __restrict__ ctx,
    const float* __restrict__ Wo,
    const float* __restrict__ bo,
    const float* __restrict__ q0,
    float* __restrict__ out, int n)
{
    int gid = blockIdx.x * blockDim.x + threadIdx.x;
    if (gid >= n) return;
    int row = gid >> 4, j = gid & 15;
    const float* c = ctx + (size_t)row * 16;
    float acc = bo[j];
#pragma unroll
    for (int i = 0; i < 16; ++i) acc += c[i] * Wo[j * 16 + i];
    out[gid] = acc + q0[gid];
}

extern "C" void kernel_launch(void* const* d_in, const int* in_sizes, int n_in,
                              void* d_out, int out_size, void* d_ws, size_t ws_size,
                              hipStream_t stream) {
    const float* query = (const float*)d_in[0];
    const float* key_  = (const float*)d_in[1];
    const float* value = (const float*)d_in[2];
    const float* w     = (const float*)d_in[3];
    const float* mask  = (const float*)d_in[4];
    const float* ln_qg = (const float*)d_in[5];
    const float* ln_qb = (const float*)d_in[6];
    const float* ln_kg = (const float*)d_in[7];
    const float* ln_kb = (const float*)d_in[8];
    const float* ln_vg = (const float*)d_in[9];
    const float* ln_vb = (const float*)d_in[10];
    const float* Wq = (const float*)d_in[11];
    const float* bq = (const float*)d_in[12];
    const float* Wk = (const float*)d_in[13];
    const float* bk = (const float*)d_in[14];
    const float* Wv = (const float*)d_in[15];
    const float* bv = (const float*)d_in[16];
    const float* Wo = (const float*)d_in[17];
    const float* bo = (const float*)d_in[18];

    float* out  = (float*)d_out;                       // (B,LQ,16) first
    float* attn = out + (size_t)BATCH * LQ * DIM;      // then (B,H,LQ,LK)

    const size_t NE = (size_t)BATCH * LQ * DIM;        // 131072
    float* ws  = (float*)d_ws;
    float* Qb  = ws;                          // 131072 f
    float* q0  = Qb + NE;                     // 131072 f
    float* ctx = q0 + NE;                     // 131072 f
    unsigned* Kh = (unsigned*)(ctx + NE);     // 65536 u32  (8 panels x 8192)
    unsigned short* Vh16 = (unsigned short*)(Kh + 65536);  // 131072 u16
    unsigned* Vh = (unsigned*)Vh16;           // u32 view: [bh][d][1024]

    ln_proj3_kernel<<<(3 * 8192) / 256, 256, 0, stream>>>(
        query, key_, value,
        ln_qg, ln_qb, ln_kg, ln_kb, ln_vg, ln_vb,
        Wq, bq, Wk, bk, Wv, bv,
        Qb, Kh, Vh16, q0);

    // 2048 blocks: 8 bh panels x 256 blocks, 8 q-rows per block
    attn_kernel<<<BATCH * HEADS * LQ / 8, 512, 0, stream>>>(
        Qb, Kh, Vh, w, mask, attn, ctx);

    out_kernel<<<((int)NE + 255) / 256, 256, 0, stream>>>(
        ctx, Wo, bo, q0, out, (int)NE);
}

// Round 11
// 83.979 us; speedup vs baseline: 1.3433x; 1.0137x over previous
//
#include <hip/hip_runtime.h>
#include <math.h>

#define BATCH 4
#define LQ 2048
#define LK 2048
#define DIM 16
#define HEADS 2
#define DH 8
#define EPS 1e-5f

typedef float fvec4 __attribute__((ext_vector_type(4)));
typedef unsigned int uvec4 __attribute__((ext_vector_type(4)));
typedef unsigned int uvec2 __attribute__((ext_vector_type(2)));
typedef __fp16 hvec2 __attribute__((ext_vector_type(2)));   // matches builtin sigs

__device__ __forceinline__ hvec2 u2h(unsigned u) {
    union { unsigned u; hvec2 h; } c; c.u = u; return c.h;
}
__device__ __forceinline__ unsigned h2u(hvec2 h) {
    union { unsigned u; hvec2 h; } c; c.h = h; return c.u;
}

// ---------------- Kernel A: fused LayerNorm + Linear for q,k,v ------------
// Q: fp32 (B,H,L,DH) pre-scaled. K: fp16 half2 dim-pairs Kh[bh][p][col]
// (p = dim pair 0..3). V: fp16 scalar Vh[bh][d][col]. Both attn-ready.
__global__ __launch_bounds__(256) void ln_proj3_kernel(
    const float* __restrict__ xq, const float* __restrict__ xk,
    const float* __restrict__ xv,
    const float* __restrict__ gq, const float* __restrict__ bq_ln,
    const float* __restrict__ gk, const float* __restrict__ bk_ln,
    const float* __restrict__ gv, const float* __restrict__ bv_ln,
    const float* __restrict__ Wq, const float* __restrict__ bq,
    const float* __restrict__ Wk, const float* __restrict__ bk,
    const float* __restrict__ Wv, const float* __restrict__ bv,
    float* __restrict__ Qb, unsigned* __restrict__ Kh,
    unsigned short* __restrict__ Vh, float* __restrict__ q0)
{
    const int gid = blockIdx.x * blockDim.x + threadIdx.x;
    const int which = gid >> 13;          // 0=q 1=k 2=v (uniform per block)
    const int r     = gid & 8191;

    const float* x; const float* g; const float* bl;
    const float* W; const float* bb; float scale;
    if (which == 0)      { x = xq; g = gq; bl = bq_ln; W = Wq; bb = bq; scale = 0.35355339059327373f; }
    else if (which == 1) { x = xk; g = gk; bl = bk_ln; W = Wk; bb = bk; scale = 1.0f; }
    else                 { x = xv; g = gv; bl = bv_ln; W = Wv; bb = bv; scale = 1.0f; }

    float xv16[16];
    const float4* xp = (const float4*)(x + (size_t)r * 16);
#pragma unroll
    for (int i = 0; i < 4; ++i) {
        float4 t = xp[i];
        xv16[4*i+0] = t.x; xv16[4*i+1] = t.y; xv16[4*i+2] = t.z; xv16[4*i+3] = t.w;
    }
    float m = 0.f;
#pragma unroll
    for (int i = 0; i < 16; ++i) m += xv16[i];
    m *= (1.f / 16.f);
    float var = 0.f;
#pragma unroll
    for (int i = 0; i < 16; ++i) { float d = xv16[i] - m; var += d * d; }
    var *= (1.f / 16.f);
    float rs = rsqrtf(var + EPS);

    float xn[16];
#pragma unroll
    for (int i = 0; i < 16; ++i) xn[i] = (xv16[i] - m) * rs * g[i] + bl[i];

    if (which == 0) {
        float4* op = (float4*)(q0 + (size_t)r * 16);
#pragma unroll
        for (int i = 0; i < 4; ++i) {
            float4 t; t.x = xn[4*i+0]; t.y = xn[4*i+1]; t.z = xn[4*i+2]; t.w = xn[4*i+3];
            op[i] = t;
        }
    }

    float pr[16];
#pragma unroll
    for (int j = 0; j < 16; ++j) {
        float acc = bb[j];
#pragma unroll
        for (int i = 0; i < 16; ++i) acc += xn[i] * W[j * 16 + i];
        pr[j] = acc * scale;
    }

    const int b = r >> 11;
    const int l = r & 2047;
    if (which == 0) {
#pragma unroll
        for (int j = 0; j < 16; ++j) {
            int h = j >> 3, d = j & 7;
            Qb[((((size_t)b * HEADS + h) * 2048) + l) * DH + d] = pr[j];
        }
    } else if (which == 1) {
#pragma unroll
        for (int h = 0; h < 2; ++h) {
            unsigned* Kpan = Kh + ((size_t)(b * 2 + h)) * 8192;
#pragma unroll
            for (int p = 0; p < 4; ++p) {
                hvec2 hk = __builtin_amdgcn_cvt_pkrtz(pr[h * 8 + 2 * p], pr[h * 8 + 2 * p + 1]);
                Kpan[p * 2048 + l] = h2u(hk);
            }
        }
    } else {
#pragma unroll
        for (int h = 0; h < 2; ++h) {
            unsigned short* Vpan = Vh + ((size_t)(b * 2 + h)) * 16384;
#pragma unroll
            for (int d = 0; d < 8; ++d) {
                union { __fp16 h; unsigned short u; } cv;
                cv.h = (__fp16)pr[h * 8 + d];
                Vpan[d * 2048 + l] = cv.u;
            }
        }
    }
}

// ---- Kernel B: full fp16 K/V panel in LDS (64KB, ONE barrier) + v_dot2,
//      depth-4 software-pipelined w/mask loads (8 in flight per wave) ------
__device__ __forceinline__ float wave_sum(float v) {
#pragma unroll
    for (int off = 32; off > 0; off >>= 1) v += __shfl_xor(v, off);
    return v;
}

// (512,2): proven no-spill cap (>=128 VGPR). (512,4)/(1024,4) forced 64-cap
// and spilled (r3, r5). Do not change.
__global__ __launch_bounds__(512, 2) void attn_kernel(
    const float* __restrict__ Q,          // (B,H,LQ,DH) pre-scaled
    const unsigned* __restrict__ Kh,      // [bh][p][2048] half2 dim-pairs
    const unsigned* __restrict__ Vh,      // [bh][d][1024] half2 col-pairs (u32 view)
    const float* __restrict__ w,
    const float* __restrict__ mask,
    float* __restrict__ attn_out,
    float* __restrict__ ctx)
{
    __shared__ unsigned Kp[4][2048];   // 32 KB: dim-pair p, all 2048 cols
    __shared__ unsigned Vp[8][1024];   // 32 KB: dim d, col-pairs

    const int t    = threadIdx.x;
    const int lane = t & 63;
    const int wid  = t >> 6;                 // 0..7, one q-row per wave
    const int bh   = blockIdx.x >> 8;        // 8 panels x 256 blocks
    const int qbase= (blockIdx.x & 255) << 3;
    const int q    = qbase + wid;
    const int rowid= (bh << 11) + q;
    const int h    = bh & (HEADS - 1);
    const int b    = bh >> 1;

    const unsigned* Kpan = Kh + (size_t)bh * 8192;
    const unsigned* Vpan = Vh + (size_t)bh * 8192;

    // ---- stage FULL panel (L2-hot; pure u32 copies) ----
    {
        const int c = t << 1;                 // col pair base for K
#pragma unroll
        for (int half = 0; half < 2; ++half) {
            const int cc = c + (half << 10);
#pragma unroll
            for (int p = 0; p < 4; ++p)
                *(uvec2*)&Kp[p][cc] = *(const uvec2*)&Kpan[p * 2048 + cc];
        }
#pragma unroll
        for (int half = 0; half < 2; ++half) {
            const int cp = t + (half << 9);   // col-pair index
#pragma unroll
            for (int d = 0; d < 8; ++d)
                Vp[d][cp] = Vpan[d * 1024 + cp];
        }
    }

    // q -> 4 packed half2 dim-pairs
    const float* Qrow = Q + (size_t)rowid * DH;
    hvec2 qpk[4];
#pragma unroll
    for (int p = 0; p < 4; ++p) qpk[p] = __builtin_amdgcn_cvt_pkrtz(Qrow[2 * p], Qrow[2 * p + 1]);

    const float* wrow = w    + (size_t)rowid * LK;
    const float* mrow = mask + (size_t)rowid * LK;

    // ---- prologue: issue 8 loads (groups 0..3) before the barrier ----
    fvec4 wb[4], mb[4];
#pragma unroll
    for (int g = 0; g < 4; ++g) {
        const int col = (g << 8) + (lane << 2);
        wb[g] = __builtin_nontemporal_load((const fvec4*)(wrow + col));
        mb[g] = __builtin_nontemporal_load((const fvec4*)(mrow + col));
    }

    __syncthreads();   // the ONLY barrier

    unsigned epk[16];            // e as half2 col-pairs
    float sum = 0.f;
    float cd[8] = {0,0,0,0,0,0,0,0};

#pragma unroll
    for (int i = 0; i < 8; ++i) {
        fvec4 wv = wb[i & 3], mv = mb[i & 3];
        if (i < 4) {           // refill slot with group i+4 (depth-4 pipeline)
            const int ncol = ((i + 4) << 8) + (lane << 2);
            wb[i & 3] = __builtin_nontemporal_load((const fvec4*)(wrow + ncol));
            mb[i & 3] = __builtin_nontemporal_load((const fvec4*)(mrow + ncol));
        }
        const int cb = (i << 8) + (lane << 2);
        uvec4 kk0 = *(const uvec4*)&Kp[0][cb];
        uvec4 kk1 = *(const uvec4*)&Kp[1][cb];
        uvec4 kk2 = *(const uvec4*)&Kp[2][cb];
        uvec4 kk3 = *(const uvec4*)&Kp[3][cb];
        float e[4];
#pragma unroll
        for (int j = 0; j < 4; ++j) {
            // -4 shift: softmax-invariant, keeps e in fp16 range
            float sj = wv[j] + mv[j] - 4.0f;
            sj = __builtin_amdgcn_fdot2(qpk[0], u2h(kk0[j]), sj, false);
            sj = __builtin_amdgcn_fdot2(qpk[1], u2h(kk1[j]), sj, false);
            sj = __builtin_amdgcn_fdot2(qpk[2], u2h(kk2[j]), sj, false);
            sj = __builtin_amdgcn_fdot2(qpk[3], u2h(kk3[j]), sj, false);
            e[j] = __expf(sj);
        }
        sum += (e[0] + e[1]) + (e[2] + e[3]);
        hvec2 e01 = __builtin_amdgcn_cvt_pkrtz(e[0], e[1]);
        hvec2 e23 = __builtin_amdgcn_cvt_pkrtz(e[2], e[3]);
        epk[2 * i]     = h2u(e01);
        epk[2 * i + 1] = h2u(e23);
        const int cp = cb >> 1;
#pragma unroll
        for (int d = 0; d < 8; ++d) {
            uvec2 vv = *(const uvec2*)&Vp[d][cp];
            cd[d] = __builtin_amdgcn_fdot2(e01, u2h(vv.x), cd[d], false);
            cd[d] = __builtin_amdgcn_fdot2(e23, u2h(vv.y), cd[d], false);
        }
    }

    sum = wave_sum(sum);
    const float inv = 1.f / sum;

    // normalized attn row: unpack fp16 e, scale, nontemporal fvec4 stores
    float* arow = attn_out + (size_t)rowid * LK;
#pragma unroll
    for (int g = 0; g < 8; ++g) {
        const int col = (g << 8) + (lane << 2);
        hvec2 e01 = u2h(epk[2 * g]), e23 = u2h(epk[2 * g + 1]);
        fvec4 o;
        o.x = (float)e01.x * inv; o.y = (float)e01.y * inv;
        o.z = (float)e23.x * inv; o.w = (float)e23.y * inv;
        __builtin_nontemporal_store(o, (fvec4*)(arow + col));
    }

#pragma unroll
    for (int d = 0; d < 8; ++d) cd[d] = wave_sum(cd[d]) * inv;
    if (lane == 0) {
        float* cp = ctx + ((((size_t)b * LQ + q) * HEADS) + h) * DH;
        fvec4 t0; t0.x = cd[0]; t0.y = cd[1]; t0.z = cd[2]; t0.w = cd[3];
        fvec4 t1; t1.x = cd[4]; t1.y = cd[5]; t1.z = cd[6]; t1.w = cd[7];
        ((fvec4*)cp)[0] = t0;
        ((fvec4*)cp)[1] = t1;
    }
}

// ---------------- Kernel C: output projection + residual ------------------
__global__ __launch_bounds__(256) void out_kernel(
    const float* __restrict__ ctx,
    const float* __restrict__ Wo,
    const float* __restrict__ bo,
    const float* __restrict__ q0,
    float* __restrict__ out, int n)
{
    int gid = blockIdx.x * blockDim.x + threadIdx.x;
    if (gid >= n) return;
    int row = gid >> 4, j = gid & 15;
    const float* c = ctx + (size_t)row * 16;
    float acc = bo[j];
#pragma unroll
    for (int i = 0; i < 16; ++i) acc += c[i] * Wo[j * 16 + i];
    out[gid] = acc + q0[gid];
}

extern "C" void kernel_launch(void* const* d_in, const int* in_sizes, int n_in,
                              void* d_out, int out_size, void* d_ws, size_t ws_size,
                              hipStream_t stream) {
    const float* query = (const float*)d_in[0];
    const float* key_  = (const float*)d_in[1];
    const float* value = (const float*)d_in[2];
    const float* w     = (const float*)d_in[3];
    const float* mask  = (const float*)d_in[4];
    const float* ln_qg = (const float*)d_in[5];
    const float* ln_qb = (const float*)d_in[6];
    const float* ln_kg = (const float*)d_in[7];
    const float* ln_kb = (const float*)d_in[8];
    const float* ln_vg = (const float*)d_in[9];
    const float* ln_vb = (const float*)d_in[10];
    const float* Wq = (const float*)d_in[11];
    const float* bq = (const float*)d_in[12];
    const float* Wk = (const float*)d_in[13];
    const float* bk = (const float*)d_in[14];
    const float* Wv = (const float*)d_in[15];
    const float* bv = (const float*)d_in[16];
    const float* Wo = (const float*)d_in[17];
    const float* bo = (const float*)d_in[18];

    float* out  = (float*)d_out;                       // (B,LQ,16) first
    float* attn = out + (size_t)BATCH * LQ * DIM;      // then (B,H,LQ,LK)

    const size_t NE = (size_t)BATCH * LQ * DIM;        // 131072
    float* ws  = (float*)d_ws;
    float* Qb  = ws;                          // 131072 f
    float* q0  = Qb + NE;                     // 131072 f
    float* ctx = q0 + NE;                     // 131072 f
    unsigned* Kh = (unsigned*)(ctx + NE);     // 65536 u32  (8 panels x 8192)
    unsigned short* Vh16 = (unsigned short*)(Kh + 65536);  // 131072 u16
    unsigned* Vh = (unsigned*)Vh16;           // u32 view: [bh][d][1024]

    ln_proj3_kernel<<<(3 * 8192) / 256, 256, 0, stream>>>(
        query, key_, value,
        ln_qg, ln_qb, ln_kg, ln_kb, ln_vg, ln_vb,
        Wq, bq, Wk, bk, Wv, bv,
        Qb, Kh, Vh16, q0);

    // 2048 blocks: 8 bh panels x 256 blocks, 8 q-rows per block
    attn_kernel<<<BATCH * HEADS * LQ / 8, 512, 0, stream>>>(
        Qb, Kh, Vh, w, mask, attn, ctx);

    out_kernel<<<((int)NE + 255) / 256, 256, 0, stream>>>(
        ctx, Wo, bo, q0, out, (int)NE);
}